// Round 1
// baseline (213.210 us; speedup 1.0000x reference)
//
#include <hip/hip_runtime.h>
#include <math.h>

// LEnsembleFactory: L[i][j] = scale * exp(-rho/4 * ||mu_i - mu_j||^2),
// L[i][i] += exp(tanh(mu_i @ W1 + b1) @ W2 + b2).
// N=16384, D=32, rho=0.01, sigma=1.

#define NROW 16384
#define DIM 32

typedef _Float16 f16x8 __attribute__((ext_vector_type(8)));
typedef float f32x16 __attribute__((ext_vector_type(16)));

// ---------------- Kernel 1: per-row prep ----------------
// - convert mus row to f16 (for MFMA)
// - sq[i] = sum of (f16-rounded mu)^2 in fp32  (so diagonal sqd == 0 exactly)
// - foc[i] = exp(tanh(mu_i @ W1 + b1) @ W2 + b2), full fp32 (diagonal accuracy)
__global__ __launch_bounds__(256) void lens_prep(
    const float* __restrict__ mus, const float* __restrict__ W1,
    const float* __restrict__ b1, const float* __restrict__ W2,
    const float* __restrict__ b2, _Float16* __restrict__ mf,
    float* __restrict__ sq, float* __restrict__ foc) {
  const int i = blockIdx.x * blockDim.x + threadIdx.x;
  if (i >= NROW) return;

  float row[DIM];
  const float4* rp = reinterpret_cast<const float4*>(mus + (size_t)i * DIM);
#pragma unroll
  for (int q = 0; q < DIM / 4; ++q) {
    float4 v = rp[q];
    row[q * 4 + 0] = v.x;
    row[q * 4 + 1] = v.y;
    row[q * 4 + 2] = v.z;
    row[q * 4 + 3] = v.w;
  }

  // f16 convert + sq from rounded values
  float s = 0.0f;
  f16x8 h[4];
#pragma unroll
  for (int q = 0; q < 4; ++q) {
#pragma unroll
    for (int e = 0; e < 8; ++e) {
      _Float16 hv = (_Float16)row[q * 8 + e];
      h[q][e] = hv;
      float f = (float)hv;
      s = fmaf(f, f, s);
    }
  }
  f16x8* mp = reinterpret_cast<f16x8*>(mf + (size_t)i * DIM);
  mp[0] = h[0];
  mp[1] = h[1];
  mp[2] = h[2];
  mp[3] = h[3];
  sq[i] = s;

  // MLP (W1 is [in][out] row-major, W2 is [in][1])
  float acc2 = 0.0f;
#pragma unroll 4
  for (int j = 0; j < DIM; ++j) {
    float hj = b1[j];
#pragma unroll
    for (int k = 0; k < DIM; ++k) hj = fmaf(row[k], W1[k * DIM + j], hj);
    acc2 = fmaf(tanhf(hj), W2[j], acc2);
  }
  foc[i] = __expf(acc2 + b2[0]);
}

// ---------------- Kernel 2: main N x N tile kernel ----------------
// 128x128 tile per 256-thread block. 4 waves in a 2x2 grid, each wave owns a
// 64x64 subtile = 2x2 of 32x32 MFMA tiles (mfma_f32_32x32x16_f16, 2 K-halves).
// No LDS: mus_f16 is 1 MiB, L2-resident; frags loaded straight from global.
__global__ __launch_bounds__(256) void lens_main(
    const _Float16* __restrict__ mf, const float* __restrict__ sq,
    const float* __restrict__ foc, float* __restrict__ out,
    float scale, float k1) {
  const int tid = threadIdx.x;
  const int lane = tid & 63;
  const int w = tid >> 6;
  const int wr = w >> 1, wc = w & 1;
  const int lo = lane & 31, hi = lane >> 5;
  const int rbase = blockIdx.y * 128 + wr * 64;
  const int cbase = blockIdx.x * 128 + wc * 64;
  const bool diagblock = (blockIdx.x == blockIdx.y);

  // A frag: lane holds mf[row = base + (lane&31)][k = kh*16 + (lane>>5)*8 + e]
  // B frag: identical pattern with col instead of row (B = mus^T).
  // Any consistent k-permutation cancels in the dot product.
  f16x8 af[2][2], bf[2][2];
#pragma unroll
  for (int s = 0; s < 2; ++s) {
#pragma unroll
    for (int kh = 0; kh < 2; ++kh) {
      af[s][kh] = *reinterpret_cast<const f16x8*>(
          mf + (size_t)(rbase + s * 32 + lo) * DIM + kh * 16 + hi * 8);
      bf[s][kh] = *reinterpret_cast<const f16x8*>(
          mf + (size_t)(cbase + s * 32 + lo) * DIM + kh * 16 + hi * 8);
    }
  }

  f32x16 acc[2][2];
#pragma unroll
  for (int sr = 0; sr < 2; ++sr) {
#pragma unroll
    for (int sc = 0; sc < 2; ++sc) {
      f32x16 c;
#pragma unroll
      for (int e = 0; e < 16; ++e) c[e] = 0.0f;
      c = __builtin_amdgcn_mfma_f32_32x32x16_f16(af[sr][0], bf[sc][0], c, 0, 0, 0);
      c = __builtin_amdgcn_mfma_f32_32x32x16_f16(af[sr][1], bf[sc][1], c, 0, 0, 0);
      acc[sr][sc] = c;
    }
  }

  float sqc[2];
#pragma unroll
  for (int sc = 0; sc < 2; ++sc) sqc[sc] = sq[cbase + sc * 32 + lo];

  // C/D layout (HW-verified): col = lane&31, row = (r&3) + 8*(r>>2) + 4*(lane>>5)
#pragma unroll
  for (int sr = 0; sr < 2; ++sr) {
    const int r0 = rbase + sr * 32 + hi * 4;
    float sqr[16];
#pragma unroll
    for (int r = 0; r < 16; ++r) sqr[r] = sq[r0 + (r & 3) + 8 * (r >> 2)];
#pragma unroll
    for (int sc = 0; sc < 2; ++sc) {
      const int col = cbase + sc * 32 + lo;
      const float sc2 = sqc[sc];
#pragma unroll
      for (int r = 0; r < 16; ++r) {
        const int row = r0 + (r & 3) + 8 * (r >> 2);
        float t = sqr[r] + sc2 - 2.0f * acc[sr][sc][r];
        t = fmaxf(t, 0.0f);
        float v = scale * __expf(k1 * t);
        if (diagblock && row == col) v += foc[row];
        out[(size_t)row * NROW + col] = v;
      }
    }
  }
}

extern "C" void kernel_launch(void* const* d_in, const int* in_sizes, int n_in,
                              void* d_out, int out_size, void* d_ws, size_t ws_size,
                              hipStream_t stream) {
  const float* mus = (const float*)d_in[0];
  const float* W1 = (const float*)d_in[1];
  const float* b1 = (const float*)d_in[2];
  const float* W2 = (const float*)d_in[3];
  const float* b2 = (const float*)d_in[4];
  float* out = (float*)d_out;

  char* ws = (char*)d_ws;
  _Float16* mf = (_Float16*)ws;                                  // 1,048,576 B
  float* sq = (float*)(ws + (size_t)NROW * DIM * 2);             // 65,536 B
  float* foc = (float*)(ws + (size_t)NROW * DIM * 2 + NROW * 4); // 65,536 B

  const double rho = 0.01, dd = (double)DIM;
  const double pi = 3.14159265358979323846;
  const double term1 = pow(2.0 * rho, dd / 2.0);
  const double term2 = pow(2.0 * pi, (1.0 - 2.0 * rho) * dd / 2.0);
  const float scale = (float)(term1 * term2);
  const float k1 = (float)(-rho / 4.0);

  lens_prep<<<NROW / 256, 256, 0, stream>>>(mus, W1, b1, W2, b2, mf, sq, foc);

  dim3 grid(NROW / 128, NROW / 128);
  lens_main<<<grid, 256, 0, stream>>>(mf, sq, foc, out, scale, k1);
}